// Round 12
// baseline (136.647 us; speedup 1.0000x reference)
//
#include <hip/hip_runtime.h>
#include <cstdint>

#define NBATCH 4
#define NPATCH 4096
#define MAXC   5
#define NCHUNK 6                            /* col chunks (j) */
#define RBLOCKS 32                          /* 128-row blocks per batch */
#define GRID_MAIN (NBATCH * RBLOCKS * NCHUNK)   /* 768 4-wave blocks */
#define SCALE  14.285714285714286f          /* 1/T, T=0.07 */
#define SCALE2 20.609929006188747f          /* (1/T) * log2(e) */
#define LN2F   0.6931471805599453f
#define NEGH  -1.0e38f
#define NEGFILL_T -142.85714285714286f      /* NEG_FILL / T */
#define NROWS (NBATCH * NPATCH)

typedef __attribute__((ext_vector_type(8))) short short8;   // 8 bf16 (4 VGPRs)
typedef __attribute__((ext_vector_type(4))) float f32x4;
typedef __attribute__((ext_vector_type(4))) unsigned int u32x4;

__device__ __forceinline__ float fexp2(float x) { return __builtin_amdgcn_exp2f(x); }
__device__ __forceinline__ float flog2(float x) { return __builtin_amdgcn_logf(x); }  // v_log_f32 = log2

__device__ __forceinline__ unsigned short f2bf(float f) {
  uint32_t u = __builtin_bit_cast(uint32_t, f);
  u = (u + 0x7FFFu + ((u >> 16) & 1u)) >> 16;   // RNE
  return (unsigned short)u;
}

// async global->LDS, 16B per lane; LDS dest is wave-uniform base + lane*16
__device__ __forceinline__ void glds16(const void* g, void* l) {
  __builtin_amdgcn_global_load_lds(
      (const __attribute__((address_space(1))) uint32_t*)g,
      (__attribute__((address_space(3))) uint32_t*)l, 16, 0, 0);
}

// Fragment layout (srcb and tgtb): tile = 16 rows x 256 k (8 KB).
// 16B chunk (8 bf16, one row's k-octet) at uint4 index  tile*512 + kc*16 + row16.

// ---- k_aux: 2 roles ----  (R8 LDS-transpose version, frozen)
__global__ __launch_bounds__(256) void k_aux(const float* __restrict__ src,
                                             const float* __restrict__ tgt,
                                             const int* __restrict__ classes,
                                             unsigned short* __restrict__ tgtb,
                                             unsigned short* __restrict__ srcb,
                                             float* __restrict__ pos,
                                             int* __restrict__ outpos,
                                             int* __restrict__ counts) {
  int blk = blockIdx.x;
  if (blk < 512) {
    __shared__ uint4 sS[2][544], sT[2][544];   // pitch 17 u4 per kc (32 kc x 16 rows)
    int t    = threadIdx.x;
    int half = t >> 7;                         // which tile of the pair
    int tt   = t & 127;
    int tl   = blk * 2 + half;
    int row16 = tt >> 3;                       // 0..15 (read mapping unchanged)
    int kg    = tt & 7;                        // 32-k slab
    size_t rowbase = (size_t)(tl * 16 + row16) * 256 + kg * 32;
    const float4* rs  = (const float4*)(src + rowbase);
    const float4* rt_ = (const float4*)(tgt + rowbase);
    float d = 0.f;
#pragma unroll
    for (int jj = 0; jj < 4; ++jj) {           // chunk kc = kg*4 + jj
      float4 sa = rs[jj * 2], sb = rs[jj * 2 + 1];
      float4 ta = rt_[jj * 2], tb = rt_[jj * 2 + 1];
      d += sa.x * ta.x + sa.y * ta.y + sa.z * ta.z + sa.w * ta.w
         + sb.x * tb.x + sb.y * tb.y + sb.z * tb.z + sb.w * tb.w;
      union { ushort4 h[2]; uint4 u; } pk;
      int li = (kg * 4 + jj) * 17 + row16;
      pk.h[0].x = f2bf(sa.x * SCALE2); pk.h[0].y = f2bf(sa.y * SCALE2);
      pk.h[0].z = f2bf(sa.z * SCALE2); pk.h[0].w = f2bf(sa.w * SCALE2);
      pk.h[1].x = f2bf(sb.x * SCALE2); pk.h[1].y = f2bf(sb.y * SCALE2);
      pk.h[1].z = f2bf(sb.z * SCALE2); pk.h[1].w = f2bf(sb.w * SCALE2);
      sS[half][li] = pk.u;
      pk.h[0].x = f2bf(ta.x); pk.h[0].y = f2bf(ta.y);
      pk.h[0].z = f2bf(ta.z); pk.h[0].w = f2bf(ta.w);
      pk.h[1].x = f2bf(tb.x); pk.h[1].y = f2bf(tb.y);
      pk.h[1].z = f2bf(tb.z); pk.h[1].w = f2bf(tb.w);
      sT[half][li] = pk.u;
    }
    d += __shfl_xor(d, 1, 64);
    d += __shfl_xor(d, 2, 64);
    d += __shfl_xor(d, 4, 64);
    if (kg == 0) pos[tl * 16 + row16] = d * SCALE;

    __syncthreads();
    // coalesced store: 128 consecutive lanes cover 2KB contiguous fragment span
    uint4* osrc = (uint4*)srcb + (size_t)tl * 512;
    uint4* otgt = (uint4*)tgtb + (size_t)tl * 512;
#pragma unroll
    for (int c = 0; c < 4; ++c) {
      int g  = c * 128 + tt;                   // u4 index within tile (0..511)
      int li = (g >> 4) * 17 + (g & 15);
      osrc[g] = sS[half][li];
      otgt[g] = sT[half][li];
    }
    return;
  }

  __shared__ int sa[MAXC * 256];
  __shared__ int sb2[MAXC * 256];
  int b = blk - 512, t = threadIdx.x;
  int base = b * NPATCH + t * 16;
  int cv[16];
#pragma unroll
  for (int e = 0; e < 16; ++e) cv[e] = classes[base + e];
  int cnt[MAXC];
#pragma unroll
  for (int c = 0; c < MAXC; ++c) {
    cnt[c] = 0;
#pragma unroll
    for (int e = 0; e < 16; ++e)
      if (cv[e] == c) cnt[c]++;
  }
#pragma unroll
  for (int c = 0; c < MAXC; ++c) sa[c * 256 + t] = cnt[c];
  __syncthreads();

  int* rp = sa; int* wp = sb2;
  for (int d = 1; d < 256; d <<= 1) {
#pragma unroll
    for (int c = 0; c < MAXC; ++c) {
      int v = rp[c * 256 + t];
      if (t >= d) v += rp[c * 256 + t - d];
      wp[c * 256 + t] = v;
    }
    __syncthreads();
    int* tmp = rp; rp = wp; wp = tmp;
  }

  int tot[MAXC], excl[MAXC], off[MAXC + 1];
  off[0] = 0;
#pragma unroll
  for (int c = 0; c < MAXC; ++c) {
    tot[c]  = rp[c * 256 + 255];
    excl[c] = rp[c * 256 + t] - cnt[c];
    off[c + 1] = off[c] + tot[c];
  }
#pragma unroll
  for (int c = 0; c < MAXC; ++c) {
    int r = off[c] + excl[c];
#pragma unroll
    for (int e = 0; e < 16; ++e)
      if (cv[e] == c) { outpos[base + e] = r; r++; }
  }
  if (t < MAXC) counts[b * MAXC + t] = tot[t];
}

// ---------------- main fused GEMM + online lse stats -----------------------------------
// R11: T5 s_setprio on the LDS-staged structure.  R3's setprio-null was on the OLD
// TCP-bound structure (regime mismatch, catalog rule #23); the catalog's +21-39%
// (m218b/m224) is measured on exactly this regime: LDS-staged, barrier-per-tile,
// co-resident blocks at skewed phases.  Mechanism: CU scheduler favors the
// MFMA-entering wave over VALU(STATS)/load-issuing waves on the same SIMD -- direct
// attack on the measured ~14us STATS serialization.  Single variable vs R10 (which
// was null; body kept byte-identical otherwise).
__global__ __launch_bounds__(256, 3) void k_main(const unsigned short* __restrict__ srcb,
                                                 const unsigned short* __restrict__ tgtb,
                                                 const int* __restrict__ classes,
                                                 float* __restrict__ pm,
                                                 float* __restrict__ ps) {
  __shared__ u32x4 sB[3][1024];               // 3 x 16KB B-tile buffers

  const int p   = blockIdx.x;
  const int b   = p & 3;
  const int jl  = (p >> 2) & 1;
  const int rb  = (p >> 3) & 31;
  const int top = p >> 8;                     // 0..2
  const int j   = top * 2 + jl;               // 0..5
  const int t0  = (j * 64) / 3;               // 32-col tile range [t0, t1) of 128
  const int t1  = ((j + 1) * 64) / 3;         // chunks: 21,21,22,21,21,22
  const int nt  = t1 - t0;

  const int tid  = threadIdx.x;
  const int w    = tid >> 6;                  // wave 0..3 -> rowgroup
  const int lane = tid & 63;
  const int q = lane >> 4, l4 = lane & 15;
  const int rowstart = b * NPATCH + rb * 128 + w * 32;

  // ---- A fragments: 32 rows resident per wave (16 coalesced uint4 loads), pinned
  const u32x4* ap = (const u32x4*)srcb + (size_t)(b * 256 + rb * 8 + w * 2) * 512 + lane;
  u32x4 afr[2][8];
#pragma unroll
  for (int rt = 0; rt < 2; ++rt)
#pragma unroll
    for (int ks = 0; ks < 8; ++ks)
      afr[rt][ks] = ap[rt * 512 + ks * 64];
#pragma unroll
  for (int rt = 0; rt < 2; ++rt)
#pragma unroll
    for (int ks = 0; ks < 8; ++ks)
      asm volatile("" : "+v"(afr[rt][ks]));

  int rcls[2][4];
#pragma unroll
  for (int rt = 0; rt < 2; ++rt)
#pragma unroll
    for (int r = 0; r < 4; ++r) {
      rcls[rt][r] = classes[rowstart + rt * 16 + q * 4 + r];
      asm volatile("" : "+v"(rcls[rt][r]));
    }

  float m_[2][4], s_[2][4];
#pragma unroll
  for (int rt = 0; rt < 2; ++rt)
#pragma unroll
    for (int r = 0; r < 4; ++r) { m_[rt][r] = -INFINITY; s_[rt][r] = 0.f; }

  const u32x4* bstage = (const u32x4*)tgtb + (size_t)(b * 256 + t0 * 2) * 512
                      + w * 64 + lane;
  const int* clp = classes + b * NPATCH + t0 * 32 + l4;

#define STAGE(NB, IT)                                                               \
  {                                                                                 \
    const u32x4* g = bstage + (size_t)(IT) * 1024;                                  \
    _Pragma("unroll")                                                               \
    for (int r = 0; r < 4; ++r)                                                     \
      glds16(g + r * 256, &sB[NB][(r * 4 + w) * 64]);                               \
  }

#define STATS(ac, cc0, cc1)                                                         \
  {                                                                                 \
    _Pragma("unroll")                                                               \
    for (int rt = 0; rt < 2; ++rt) {                                                \
      _Pragma("unroll")                                                             \
      for (int r = 0; r < 4; ++r) {                                                 \
        int rc = rcls[rt][r];                                                       \
        float y0 = ((cc0) == rc) ? NEGH : (ac)[rt][0][r];                           \
        float y1 = ((cc1) == rc) ? NEGH : (ac)[rt][1][r];                           \
        float nm = fmaxf(m_[rt][r], fmaxf(y0, y1));                                 \
        float e01 = fexp2(y0 - nm) + fexp2(y1 - nm);                                \
        s_[rt][r] = fmaf(s_[rt][r], fexp2(m_[rt][r] - nm), e01);                    \
        m_[rt][r] = nm;                                                             \
      }                                                                             \
    }                                                                               \
  }

  // BODY: tile IT -> CUR acc; STATS on PRV acc between kh0 MFMAs and kh1 ds_reads.
  // T5: setprio(1) around each MFMA cluster so the CU scheduler prefers the
  // MFMA-entering wave over co-resident waves issuing STATS VALU / stage loads.
#define BODY(CUR, PRV, IT, DOSTATS)                                                 \
  {                                                                                 \
    const int cb_ = (IT) % 3;                                                       \
    const bool staged_ = ((IT) + 2 < nt);                                           \
    if (staged_) STAGE(((IT) + 2) % 3, (IT) + 2);                                   \
    int nc0 = clp[0];                                                               \
    int nc1 = clp[16];                                                              \
    clp += 32;                                                                      \
    {                                                                               \
      u32x4 e0[4], e1[4];                                                           \
      _Pragma("unroll")                                                             \
      for (int i = 0; i < 4; ++i) {                                                 \
        e0[i] = sB[cb_][i * 64 + lane];                                             \
        e1[i] = sB[cb_][512 + i * 64 + lane];                                       \
      }                                                                             \
      __builtin_amdgcn_s_setprio(1);                                                \
      _Pragma("unroll")                                                             \
      for (int ksl = 0; ksl < 4; ++ksl) {                                           \
        short8 b0 = __builtin_bit_cast(short8, e0[ksl]);                            \
        short8 b1 = __builtin_bit_cast(short8, e1[ksl]);                            \
        _Pragma("unroll")                                                           \
        for (int rt = 0; rt < 2; ++rt) {                                            \
          short8 a = __builtin_bit_cast(short8, afr[rt][ksl]);                      \
          CUR[rt][0] = __builtin_amdgcn_mfma_f32_16x16x32_bf16(                     \
              a, b0, (ksl == 0) ? zc : CUR[rt][0], 0, 0, 0);                        \
          CUR[rt][1] = __builtin_amdgcn_mfma_f32_16x16x32_bf16(                     \
              a, b1, (ksl == 0) ? zc : CUR[rt][1], 0, 0, 0);                        \
        }                                                                           \
      }                                                                             \
      __builtin_amdgcn_s_setprio(0);                                                \
    }                                                                               \
    if (DOSTATS) STATS(PRV, pc0, pc1);                                              \
    {                                                                               \
      u32x4 e0[4], e1[4];                                                           \
      _Pragma("unroll")                                                             \
      for (int i = 0; i < 4; ++i) {                                                 \
        e0[i] = sB[cb_][256 + i * 64 + lane];                                       \
        e1[i] = sB[cb_][768 + i * 64 + lane];                                       \
      }                                                                             \
      __builtin_amdgcn_s_setprio(1);                                                \
      _Pragma("unroll")                                                             \
      for (int ksl = 0; ksl < 4; ++ksl) {                                           \
        short8 b0 = __builtin_bit_cast(short8, e0[ksl]);                            \
        short8 b1 = __builtin_bit_cast(short8, e1[ksl]);                            \
        _Pragma("unroll")                                                           \
        for (int rt = 0; rt < 2; ++rt) {                                            \
          short8 a = __builtin_bit_cast(short8, afr[rt][4 + ksl]);                  \
          CUR[rt][0] = __builtin_amdgcn_mfma_f32_16x16x32_bf16(a, b0, CUR[rt][0], 0, 0, 0); \
          CUR[rt][1] = __builtin_amdgcn_mfma_f32_16x16x32_bf16(a, b1, CUR[rt][1], 0, 0, 0); \
        }                                                                           \
      }                                                                             \
      __builtin_amdgcn_s_setprio(0);                                                \
    }                                                                               \
    pc0 = nc0; pc1 = nc1;                                                           \
    if ((IT) + 1 < nt) {                                                            \
      if (staged_) asm volatile("s_waitcnt vmcnt(4)\n\ts_barrier" ::: "memory");    \
      else         asm volatile("s_waitcnt vmcnt(0)\n\ts_barrier" ::: "memory");    \
    }                                                                               \
  }

  const f32x4 zc = {0.f, 0.f, 0.f, 0.f};
  f32x4 accA[2][2], accB[2][2];
  int pc0 = 0, pc1 = 0;

  STAGE(0, 0);                                // prologue: tiles 0,1 -> bufs 0,1
  STAGE(1, 1);
  asm volatile("s_waitcnt vmcnt(4)\n\ts_barrier" ::: "memory");

  BODY(accA, accB, 0, 0);                     // tile 0 -> accA, no stats yet

  int it = 1;
  for (; it + 1 < nt; it += 2) {
    BODY(accB, accA, it, 1);                  // tile it   -> accB, stats(tile it-1)
    BODY(accA, accB, it + 1, 1);              // tile it+1 -> accA, stats(tile it)
  }
  if (it < nt) {                              // nt even: one leftover tile
    BODY(accB, accA, it, 1);
    STATS(accB, pc0, pc1);
  } else {                                    // nt odd: last tile is in accA
    STATS(accA, pc0, pc1);
  }
#undef STAGE
#undef STATS
#undef BODY

  // butterfly merge across the 16 col-lanes of each quad
#pragma unroll
  for (int off = 1; off < 16; off <<= 1) {
#pragma unroll
    for (int rt = 0; rt < 2; ++rt)
#pragma unroll
      for (int r = 0; r < 4; ++r) {
        float om = __shfl_xor(m_[rt][r], off, 64);
        float os = __shfl_xor(s_[rt][r], off, 64);
        float nm = fmaxf(m_[rt][r], om);
        s_[rt][r] = s_[rt][r] * fexp2(m_[rt][r] - nm) + os * fexp2(om - nm);
        m_[rt][r] = nm;
      }
  }

  if (l4 == 0) {
#pragma unroll
    for (int rt = 0; rt < 2; ++rt)
#pragma unroll
      for (int r = 0; r < 4; ++r) {
        size_t o = (size_t)j * NROWS + rowstart + rt * 16 + q * 4 + r;
        pm[o] = m_[rt][r];                     // log2 domain
        ps[o] = s_[rt][r];
      }
  }
}

// ---------------- final: merge chunk partials + pad term + scatter (grid 64) ----------
__global__ __launch_bounds__(256) void k_fin(const int* __restrict__ classes,
                                             const float* __restrict__ pos,
                                             const float* __restrict__ pm,
                                             const float* __restrict__ ps,
                                             const int* __restrict__ outpos,
                                             const int* __restrict__ counts,
                                             float* __restrict__ out) {
  int n = blockIdx.x * 256 + threadIdx.x;
  int b = n >> 12;
  int c = classes[n];
  float ps_ = pos[n];

  float M2 = -INFINITY;
  float mm[NCHUNK], ss[NCHUNK];
#pragma unroll
  for (int s = 0; s < NCHUNK; ++s) {
    mm[s] = pm[(size_t)s * NROWS + n];
    ss[s] = ps[(size_t)s * NROWS + n];
    M2 = fmaxf(M2, mm[s]);
  }
  float S2 = 0.f;
#pragma unroll
  for (int s = 0; s < NCHUNK; ++s) S2 = fmaf(ss[s], fexp2(mm[s] - M2), S2);
  float ln = (S2 > 0.f) ? (M2 + flog2(S2)) * LN2F : -INFINITY;

  int npad = counts[b * MAXC + c] - 1;
  float pt = (npad > 0) ? (logf((float)npad) + NEGFILL_T) : -INFINITY;
  float M = fmaxf(ps_, fmaxf(ln, pt));
  float lse = M + logf(expf(ps_ - M) + expf(ln - M) + expf(pt - M));
  out[b * NPATCH + outpos[n]] = lse - ps_;
}

extern "C" void kernel_launch(void* const* d_in, const int* in_sizes, int n_in,
                              void* d_out, int out_size, void* d_ws, size_t ws_size,
                              hipStream_t stream) {
  const float* src = (const float*)d_in[0];
  const float* tgt = (const float*)d_in[1];
  const int* cls   = (const int*)d_in[2];
  float* out = (float*)d_out;

  char* ws = (char*)d_ws;
  unsigned short* tgtb = (unsigned short*)(ws);            //  8,388,608 B (fragment layout)
  unsigned short* srcb = (unsigned short*)(ws + 8388608);  //  8,388,608 B (frag, pre-scaled)
  float* pos    = (float*)(ws + 16777216);                 //     65,536 B
  float* pm     = (float*)(ws + 16842752);                 //    393,216 B (6 chunk planes)
  float* ps     = (float*)(ws + 17235968);                 //    393,216 B
  int*   outpos = (int*)  (ws + 17629184);                 //     65,536 B
  int*   counts = (int*)  (ws + 17694720);                 //         80 B

  k_aux<<<512 + NBATCH, 256, 0, stream>>>(src, tgt, cls, tgtb, srcb, pos, outpos, counts);
  k_main<<<GRID_MAIN, 256, 0, stream>>>(srcb, tgtb, cls, pm, ps);
  k_fin<<<NROWS / 256, 256, 0, stream>>>(cls, pos, pm, ps, outpos, counts, out);
}

// Round 13
// 128.284 us; speedup vs baseline: 1.0652x; 1.0652x over previous
//
#include <hip/hip_runtime.h>
#include <cstdint>

#define NBATCH 4
#define NPATCH 4096
#define MAXC   5
#define NCHUNK 8                            /* col chunks (j): 16 tiles each */
#define RBLOCKS 16                          /* 256-row blocks per batch */
#define GRID_MAIN (NBATCH * RBLOCKS * NCHUNK)   /* 512 4-wave blocks = 2/CU */
#define SCALE  14.285714285714286f          /* 1/T, T=0.07 */
#define SCALE2 20.609929006188747f          /* (1/T) * log2(e) */
#define LN2F   0.6931471805599453f
#define NEGH  -1.0e38f
#define NEGFILL_T -142.85714285714286f      /* NEG_FILL / T */
#define NROWS (NBATCH * NPATCH)

typedef __attribute__((ext_vector_type(8))) short short8;   // 8 bf16 (4 VGPRs)
typedef __attribute__((ext_vector_type(4))) float f32x4;
typedef __attribute__((ext_vector_type(4))) unsigned int u32x4;

__device__ __forceinline__ float fexp2(float x) { return __builtin_amdgcn_exp2f(x); }
__device__ __forceinline__ float flog2(float x) { return __builtin_amdgcn_logf(x); }  // v_log_f32 = log2

__device__ __forceinline__ unsigned short f2bf(float f) {
  uint32_t u = __builtin_bit_cast(uint32_t, f);
  u = (u + 0x7FFFu + ((u >> 16) & 1u)) >> 16;   // RNE
  return (unsigned short)u;
}

// async global->LDS, 16B per lane; LDS dest is wave-uniform base + lane*16
__device__ __forceinline__ void glds16(const void* g, void* l) {
  __builtin_amdgcn_global_load_lds(
      (const __attribute__((address_space(1))) uint32_t*)g,
      (__attribute__((address_space(3))) uint32_t*)l, 16, 0, 0);
}

// Fragment layout (srcb and tgtb): tile = 16 rows x 256 k (8 KB).
// 16B chunk (8 bf16, one row's k-octet) at uint4 index  tile*512 + kc*16 + row16.

// ---- k_aux: 2 roles ----  (R8 LDS-transpose version, frozen)
__global__ __launch_bounds__(256) void k_aux(const float* __restrict__ src,
                                             const float* __restrict__ tgt,
                                             const int* __restrict__ classes,
                                             unsigned short* __restrict__ tgtb,
                                             unsigned short* __restrict__ srcb,
                                             float* __restrict__ pos,
                                             int* __restrict__ outpos,
                                             int* __restrict__ counts) {
  int blk = blockIdx.x;
  if (blk < 512) {
    __shared__ uint4 sS[2][544], sT[2][544];   // pitch 17 u4 per kc (32 kc x 16 rows)
    int t    = threadIdx.x;
    int half = t >> 7;                         // which tile of the pair
    int tt   = t & 127;
    int tl   = blk * 2 + half;
    int row16 = tt >> 3;                       // 0..15 (read mapping unchanged)
    int kg    = tt & 7;                        // 32-k slab
    size_t rowbase = (size_t)(tl * 16 + row16) * 256 + kg * 32;
    const float4* rs  = (const float4*)(src + rowbase);
    const float4* rt_ = (const float4*)(tgt + rowbase);
    float d = 0.f;
#pragma unroll
    for (int jj = 0; jj < 4; ++jj) {           // chunk kc = kg*4 + jj
      float4 sa = rs[jj * 2], sb = rs[jj * 2 + 1];
      float4 ta = rt_[jj * 2], tb = rt_[jj * 2 + 1];
      d += sa.x * ta.x + sa.y * ta.y + sa.z * ta.z + sa.w * ta.w
         + sb.x * tb.x + sb.y * tb.y + sb.z * tb.z + sb.w * tb.w;
      union { ushort4 h[2]; uint4 u; } pk;
      int li = (kg * 4 + jj) * 17 + row16;
      pk.h[0].x = f2bf(sa.x * SCALE2); pk.h[0].y = f2bf(sa.y * SCALE2);
      pk.h[0].z = f2bf(sa.z * SCALE2); pk.h[0].w = f2bf(sa.w * SCALE2);
      pk.h[1].x = f2bf(sb.x * SCALE2); pk.h[1].y = f2bf(sb.y * SCALE2);
      pk.h[1].z = f2bf(sb.z * SCALE2); pk.h[1].w = f2bf(sb.w * SCALE2);
      sS[half][li] = pk.u;
      pk.h[0].x = f2bf(ta.x); pk.h[0].y = f2bf(ta.y);
      pk.h[0].z = f2bf(ta.z); pk.h[0].w = f2bf(ta.w);
      pk.h[1].x = f2bf(tb.x); pk.h[1].y = f2bf(tb.y);
      pk.h[1].z = f2bf(tb.z); pk.h[1].w = f2bf(tb.w);
      sT[half][li] = pk.u;
    }
    d += __shfl_xor(d, 1, 64);
    d += __shfl_xor(d, 2, 64);
    d += __shfl_xor(d, 4, 64);
    if (kg == 0) pos[tl * 16 + row16] = d * SCALE;

    __syncthreads();
    // coalesced store: 128 consecutive lanes cover 2KB contiguous fragment span
    uint4* osrc = (uint4*)srcb + (size_t)tl * 512;
    uint4* otgt = (uint4*)tgtb + (size_t)tl * 512;
#pragma unroll
    for (int c = 0; c < 4; ++c) {
      int g  = c * 128 + tt;                   // u4 index within tile (0..511)
      int li = (g >> 4) * 17 + (g & 15);
      osrc[g] = sS[half][li];
      otgt[g] = sT[half][li];
    }
    return;
  }

  __shared__ int sa[MAXC * 256];
  __shared__ int sb2[MAXC * 256];
  int b = blk - 512, t = threadIdx.x;
  int base = b * NPATCH + t * 16;
  int cv[16];
#pragma unroll
  for (int e = 0; e < 16; ++e) cv[e] = classes[base + e];
  int cnt[MAXC];
#pragma unroll
  for (int c = 0; c < MAXC; ++c) {
    cnt[c] = 0;
#pragma unroll
    for (int e = 0; e < 16; ++e)
      if (cv[e] == c) cnt[c]++;
  }
#pragma unroll
  for (int c = 0; c < MAXC; ++c) sa[c * 256 + t] = cnt[c];
  __syncthreads();

  int* rp = sa; int* wp = sb2;
  for (int d = 1; d < 256; d <<= 1) {
#pragma unroll
    for (int c = 0; c < MAXC; ++c) {
      int v = rp[c * 256 + t];
      if (t >= d) v += rp[c * 256 + t - d];
      wp[c * 256 + t] = v;
    }
    __syncthreads();
    int* tmp = rp; rp = wp; wp = tmp;
  }

  int tot[MAXC], excl[MAXC], off[MAXC + 1];
  off[0] = 0;
#pragma unroll
  for (int c = 0; c < MAXC; ++c) {
    tot[c]  = rp[c * 256 + 255];
    excl[c] = rp[c * 256 + t] - cnt[c];
    off[c + 1] = off[c] + tot[c];
  }
#pragma unroll
  for (int c = 0; c < MAXC; ++c) {
    int r = off[c] + excl[c];
#pragma unroll
    for (int e = 0; e < 16; ++e)
      if (cv[e] == c) { outpos[base + e] = r; r++; }
  }
  if (t < MAXC) counts[b * MAXC + t] = tot[t];
}

// ---------------- main fused GEMM + online lse stats -----------------------------------
// R13: 64 rows per wave (BM=256 block).  Binding resource identified across R1-R12:
// per-CU LDS read BW -- every wave streams the whole 16KB B tile, so bytes/FLOP only
// drops with more rows/wave.  Register arithmetic (vs R10's measured 148 unified ->
// 8 waves/CU, pool ~512/SIMD): afr 128 + acc 32 + temps ~70 = ~230-250 -> 2 waves/SIMD
// still fit -> occupancy UNCHANGED, LDS-bytes/FLOP HALVED.  Grid 512 = 2 blocks/CU
// exactly.  Ledger-driven simplifications: no pins (R5 null), no acc ping-pong (R10
// null), no gate (R9 worse), no setprio (R11 worse).  R7 3-buffer counted-vmcnt kept.
__global__ __launch_bounds__(256, 2) void k_main(const unsigned short* __restrict__ srcb,
                                                 const unsigned short* __restrict__ tgtb,
                                                 const int* __restrict__ classes,
                                                 float* __restrict__ pm,
                                                 float* __restrict__ ps) {
  __shared__ u32x4 sB[3][1024];               // 3 x 16KB B-tile buffers

  const int p   = blockIdx.x;
  const int b   = p & 3;                      // batch (XCD-paired under %8 round-robin)
  const int jl  = (p >> 2) & 1;
  const int rb  = (p >> 3) & 15;              // 256-row block
  const int top = p >> 7;                     // 0..3
  const int j   = top * 2 + jl;               // chunk 0..7
  const int t0  = j * 16;                     // 16 32-col tiles per chunk
  const int nt  = 16;

  const int tid  = threadIdx.x;
  const int w    = tid >> 6;                  // wave 0..3 -> 64-row group
  const int lane = tid & 63;
  const int q = lane >> 4, l4 = lane & 15;
  const int rowstart = b * NPATCH + rb * 256 + w * 64;

  // ---- A fragments: 64 rows resident per wave (32 coalesced uint4 loads)
  const u32x4* ap = (const u32x4*)srcb + (size_t)(b * 256 + rb * 16 + w * 4) * 512 + lane;
  u32x4 afr[4][8];
#pragma unroll
  for (int rt = 0; rt < 4; ++rt)
#pragma unroll
    for (int ks = 0; ks < 8; ++ks)
      afr[rt][ks] = ap[rt * 512 + ks * 64];

  int rcls[4][4];
#pragma unroll
  for (int rt = 0; rt < 4; ++rt)
#pragma unroll
    for (int r = 0; r < 4; ++r)
      rcls[rt][r] = classes[rowstart + rt * 16 + q * 4 + r];

  float m_[4][4], s_[4][4];
#pragma unroll
  for (int rt = 0; rt < 4; ++rt)
#pragma unroll
    for (int r = 0; r < 4; ++r) { m_[rt][r] = -INFINITY; s_[rt][r] = 0.f; }

  const u32x4* bstage = (const u32x4*)tgtb + (size_t)(b * 256 + t0 * 2) * 512
                      + w * 64 + lane;
  const int* clp = classes + b * NPATCH + t0 * 32 + l4;

#define STAGE(NB, IT)                                                               \
  {                                                                                 \
    const u32x4* g = bstage + (size_t)(IT) * 1024;                                  \
    _Pragma("unroll")                                                               \
    for (int r = 0; r < 4; ++r)                                                     \
      glds16(g + r * 256, &sB[NB][(r * 4 + w) * 64]);                               \
  }

#define STATS(ac, cc0, cc1)                                                         \
  {                                                                                 \
    _Pragma("unroll")                                                               \
    for (int rt = 0; rt < 4; ++rt) {                                                \
      _Pragma("unroll")                                                             \
      for (int r = 0; r < 4; ++r) {                                                 \
        int rc = rcls[rt][r];                                                       \
        float y0 = ((cc0) == rc) ? NEGH : (ac)[rt][0][r];                           \
        float y1 = ((cc1) == rc) ? NEGH : (ac)[rt][1][r];                           \
        float nm = fmaxf(m_[rt][r], fmaxf(y0, y1));                                 \
        float e01 = fexp2(y0 - nm) + fexp2(y1 - nm);                                \
        s_[rt][r] = fmaf(s_[rt][r], fexp2(m_[rt][r] - nm), e01);                    \
        m_[rt][r] = nm;                                                             \
      }                                                                             \
    }                                                                               \
  }

  const f32x4 zc = {0.f, 0.f, 0.f, 0.f};

  STAGE(0, 0);                                // prologue: tiles 0,1 -> bufs 0,1
  STAGE(1, 1);
  asm volatile("s_waitcnt vmcnt(4)\n\ts_barrier" ::: "memory");

  for (int it = 0; it < nt; ++it) {
    const int cb = it % 3;
    const bool staged = (it + 2 < nt);
    if (staged) STAGE((it + 2) % 3, it + 2);  // 2-deep prefetch

    int c0 = clp[0];                          // this tile's column classes
    int c1 = clp[16];
    clp += 32;

    f32x4 acc[4][2];
    {                                         // kh = 0
      u32x4 e0[4], e1[4];
#pragma unroll
      for (int i = 0; i < 4; ++i) {
        e0[i] = sB[cb][i * 64 + lane];
        e1[i] = sB[cb][512 + i * 64 + lane];
      }
#pragma unroll
      for (int ksl = 0; ksl < 4; ++ksl) {
        short8 b0 = __builtin_bit_cast(short8, e0[ksl]);
        short8 b1 = __builtin_bit_cast(short8, e1[ksl]);
#pragma unroll
        for (int rt = 0; rt < 4; ++rt) {
          short8 a = __builtin_bit_cast(short8, afr[rt][ksl]);
          acc[rt][0] = __builtin_amdgcn_mfma_f32_16x16x32_bf16(
              a, b0, (ksl == 0) ? zc : acc[rt][0], 0, 0, 0);
          acc[rt][1] = __builtin_amdgcn_mfma_f32_16x16x32_bf16(
              a, b1, (ksl == 0) ? zc : acc[rt][1], 0, 0, 0);
        }
      }
    }
    {                                         // kh = 1
      u32x4 e0[4], e1[4];
#pragma unroll
      for (int i = 0; i < 4; ++i) {
        e0[i] = sB[cb][256 + i * 64 + lane];
        e1[i] = sB[cb][768 + i * 64 + lane];
      }
#pragma unroll
      for (int ksl = 0; ksl < 4; ++ksl) {
        short8 b0 = __builtin_bit_cast(short8, e0[ksl]);
        short8 b1 = __builtin_bit_cast(short8, e1[ksl]);
#pragma unroll
        for (int rt = 0; rt < 4; ++rt) {
          short8 a = __builtin_bit_cast(short8, afr[rt][4 + ksl]);
          acc[rt][0] = __builtin_amdgcn_mfma_f32_16x16x32_bf16(a, b0, acc[rt][0], 0, 0, 0);
          acc[rt][1] = __builtin_amdgcn_mfma_f32_16x16x32_bf16(a, b1, acc[rt][1], 0, 0, 0);
        }
      }
    }

    STATS(acc, c0, c1);

    if (it + 1 < nt) {
      if (staged) asm volatile("s_waitcnt vmcnt(4)\n\ts_barrier" ::: "memory");
      else        asm volatile("s_waitcnt vmcnt(0)\n\ts_barrier" ::: "memory");
    }
  }
#undef STAGE
#undef STATS

  // butterfly merge across the 16 col-lanes of each quad
#pragma unroll
  for (int off = 1; off < 16; off <<= 1) {
#pragma unroll
    for (int rt = 0; rt < 4; ++rt)
#pragma unroll
      for (int r = 0; r < 4; ++r) {
        float om = __shfl_xor(m_[rt][r], off, 64);
        float os = __shfl_xor(s_[rt][r], off, 64);
        float nm = fmaxf(m_[rt][r], om);
        s_[rt][r] = s_[rt][r] * fexp2(m_[rt][r] - nm) + os * fexp2(om - nm);
        m_[rt][r] = nm;
      }
  }

  if (l4 == 0) {
#pragma unroll
    for (int rt = 0; rt < 4; ++rt)
#pragma unroll
      for (int r = 0; r < 4; ++r) {
        size_t o = (size_t)j * NROWS + rowstart + rt * 16 + q * 4 + r;
        pm[o] = m_[rt][r];                     // log2 domain
        ps[o] = s_[rt][r];
      }
  }
}

// ---------------- final: merge chunk partials + pad term + scatter (grid 64) ----------
__global__ __launch_bounds__(256) void k_fin(const int* __restrict__ classes,
                                             const float* __restrict__ pos,
                                             const float* __restrict__ pm,
                                             const float* __restrict__ ps,
                                             const int* __restrict__ outpos,
                                             const int* __restrict__ counts,
                                             float* __restrict__ out) {
  int n = blockIdx.x * 256 + threadIdx.x;
  int b = n >> 12;
  int c = classes[n];
  float ps_ = pos[n];

  float M2 = -INFINITY;
  float mm[NCHUNK], ss[NCHUNK];
#pragma unroll
  for (int s = 0; s < NCHUNK; ++s) {
    mm[s] = pm[(size_t)s * NROWS + n];
    ss[s] = ps[(size_t)s * NROWS + n];
    M2 = fmaxf(M2, mm[s]);
  }
  float S2 = 0.f;
#pragma unroll
  for (int s = 0; s < NCHUNK; ++s) S2 = fmaf(ss[s], fexp2(mm[s] - M2), S2);
  float ln = (S2 > 0.f) ? (M2 + flog2(S2)) * LN2F : -INFINITY;

  int npad = counts[b * MAXC + c] - 1;
  float pt = (npad > 0) ? (logf((float)npad) + NEGFILL_T) : -INFINITY;
  float M = fmaxf(ps_, fmaxf(ln, pt));
  float lse = M + logf(expf(ps_ - M) + expf(ln - M) + expf(pt - M));
  out[b * NPATCH + outpos[n]] = lse - ps_;
}

extern "C" void kernel_launch(void* const* d_in, const int* in_sizes, int n_in,
                              void* d_out, int out_size, void* d_ws, size_t ws_size,
                              hipStream_t stream) {
  const float* src = (const float*)d_in[0];
  const float* tgt = (const float*)d_in[1];
  const int* cls   = (const int*)d_in[2];
  float* out = (float*)d_out;

  char* ws = (char*)d_ws;
  unsigned short* tgtb = (unsigned short*)(ws);            //  8,388,608 B (fragment layout)
  unsigned short* srcb = (unsigned short*)(ws + 8388608);  //  8,388,608 B (frag, pre-scaled)
  float* pos    = (float*)(ws + 16777216);                 //     65,536 B
  float* pm     = (float*)(ws + 16842752);                 //    524,288 B (8 chunk planes)
  float* ps     = (float*)(ws + 17367040);                 //    524,288 B
  int*   outpos = (int*)  (ws + 17891328);                 //     65,536 B
  int*   counts = (int*)  (ws + 17956864);                 //         80 B

  k_aux<<<512 + NBATCH, 256, 0, stream>>>(src, tgt, cls, tgtb, srcb, pos, outpos, counts);
  k_main<<<GRID_MAIN, 256, 0, stream>>>(srcb, tgtb, cls, pm, ps);
  k_fin<<<NROWS / 256, 256, 0, stream>>>(cls, pos, pm, ps, outpos, counts, out);
}

// Round 14
// 126.282 us; speedup vs baseline: 1.0821x; 1.0159x over previous
//
#include <hip/hip_runtime.h>
#include <cstdint>

#define NBATCH 4
#define NPATCH 4096
#define MAXC   5
#define NCHUNK 6                            /* col chunks (j) */
#define RBLOCKS 32                          /* 128-row blocks per batch */
#define GRID_MAIN (NBATCH * RBLOCKS * NCHUNK)   /* 768 8-wave blocks = 3/CU */
#define SCALE  14.285714285714286f          /* 1/T, T=0.07 */
#define SCALE2 20.609929006188747f          /* (1/T) * log2(e) */
#define LN2F   0.6931471805599453f
#define NEGH  -1.0e38f
#define NEGFILL_T -142.85714285714286f      /* NEG_FILL / T */
#define NROWS (NBATCH * NPATCH)

typedef __attribute__((ext_vector_type(8))) short short8;   // 8 bf16 (4 VGPRs)
typedef __attribute__((ext_vector_type(4))) float f32x4;
typedef __attribute__((ext_vector_type(4))) unsigned int u32x4;

__device__ __forceinline__ float fexp2(float x) { return __builtin_amdgcn_exp2f(x); }
__device__ __forceinline__ float flog2(float x) { return __builtin_amdgcn_logf(x); }  // v_log_f32 = log2

__device__ __forceinline__ unsigned short f2bf(float f) {
  uint32_t u = __builtin_bit_cast(uint32_t, f);
  u = (u + 0x7FFFu + ((u >> 16) & 1u)) >> 16;   // RNE
  return (unsigned short)u;
}

// async global->LDS, 16B per lane; LDS dest is wave-uniform base + lane*16
__device__ __forceinline__ void glds16(const void* g, void* l) {
  __builtin_amdgcn_global_load_lds(
      (const __attribute__((address_space(1))) uint32_t*)g,
      (__attribute__((address_space(3))) uint32_t*)l, 16, 0, 0);
}

// Fragment layout (srcb and tgtb): tile = 16 rows x 256 k (8 KB).
// 16B chunk (8 bf16, one row's k-octet) at uint4 index  tile*512 + kc*16 + row16.

// ---- k_aux: 2 roles ----  (R8 LDS-transpose version, frozen)
__global__ __launch_bounds__(256) void k_aux(const float* __restrict__ src,
                                             const float* __restrict__ tgt,
                                             const int* __restrict__ classes,
                                             unsigned short* __restrict__ tgtb,
                                             unsigned short* __restrict__ srcb,
                                             float* __restrict__ pos,
                                             int* __restrict__ outpos,
                                             int* __restrict__ counts) {
  int blk = blockIdx.x;
  if (blk < 512) {
    __shared__ uint4 sS[2][544], sT[2][544];   // pitch 17 u4 per kc (32 kc x 16 rows)
    int t    = threadIdx.x;
    int half = t >> 7;                         // which tile of the pair
    int tt   = t & 127;
    int tl   = blk * 2 + half;
    int row16 = tt >> 3;                       // 0..15 (read mapping unchanged)
    int kg    = tt & 7;                        // 32-k slab
    size_t rowbase = (size_t)(tl * 16 + row16) * 256 + kg * 32;
    const float4* rs  = (const float4*)(src + rowbase);
    const float4* rt_ = (const float4*)(tgt + rowbase);
    float d = 0.f;
#pragma unroll
    for (int jj = 0; jj < 4; ++jj) {           // chunk kc = kg*4 + jj
      float4 sa = rs[jj * 2], sb = rs[jj * 2 + 1];
      float4 ta = rt_[jj * 2], tb = rt_[jj * 2 + 1];
      d += sa.x * ta.x + sa.y * ta.y + sa.z * ta.z + sa.w * ta.w
         + sb.x * tb.x + sb.y * tb.y + sb.z * tb.z + sb.w * tb.w;
      union { ushort4 h[2]; uint4 u; } pk;
      int li = (kg * 4 + jj) * 17 + row16;
      pk.h[0].x = f2bf(sa.x * SCALE2); pk.h[0].y = f2bf(sa.y * SCALE2);
      pk.h[0].z = f2bf(sa.z * SCALE2); pk.h[0].w = f2bf(sa.w * SCALE2);
      pk.h[1].x = f2bf(sb.x * SCALE2); pk.h[1].y = f2bf(sb.y * SCALE2);
      pk.h[1].z = f2bf(sb.z * SCALE2); pk.h[1].w = f2bf(sb.w * SCALE2);
      sS[half][li] = pk.u;
      pk.h[0].x = f2bf(ta.x); pk.h[0].y = f2bf(ta.y);
      pk.h[0].z = f2bf(ta.z); pk.h[0].w = f2bf(ta.w);
      pk.h[1].x = f2bf(tb.x); pk.h[1].y = f2bf(tb.y);
      pk.h[1].z = f2bf(tb.z); pk.h[1].w = f2bf(tb.w);
      sT[half][li] = pk.u;
    }
    d += __shfl_xor(d, 1, 64);
    d += __shfl_xor(d, 2, 64);
    d += __shfl_xor(d, 4, 64);
    if (kg == 0) pos[tl * 16 + row16] = d * SCALE;

    __syncthreads();
    // coalesced store: 128 consecutive lanes cover 2KB contiguous fragment span
    uint4* osrc = (uint4*)srcb + (size_t)tl * 512;
    uint4* otgt = (uint4*)tgtb + (size_t)tl * 512;
#pragma unroll
    for (int c = 0; c < 4; ++c) {
      int g  = c * 128 + tt;                   // u4 index within tile (0..511)
      int li = (g >> 4) * 17 + (g & 15);
      osrc[g] = sS[half][li];
      otgt[g] = sT[half][li];
    }
    return;
  }

  __shared__ int sa[MAXC * 256];
  __shared__ int sb2[MAXC * 256];
  int b = blk - 512, t = threadIdx.x;
  int base = b * NPATCH + t * 16;
  int cv[16];
#pragma unroll
  for (int e = 0; e < 16; ++e) cv[e] = classes[base + e];
  int cnt[MAXC];
#pragma unroll
  for (int c = 0; c < MAXC; ++c) {
    cnt[c] = 0;
#pragma unroll
    for (int e = 0; e < 16; ++e)
      if (cv[e] == c) cnt[c]++;
  }
#pragma unroll
  for (int c = 0; c < MAXC; ++c) sa[c * 256 + t] = cnt[c];
  __syncthreads();

  int* rp = sa; int* wp = sb2;
  for (int d = 1; d < 256; d <<= 1) {
#pragma unroll
    for (int c = 0; c < MAXC; ++c) {
      int v = rp[c * 256 + t];
      if (t >= d) v += rp[c * 256 + t - d];
      wp[c * 256 + t] = v;
    }
    __syncthreads();
    int* tmp = rp; rp = wp; wp = tmp;
  }

  int tot[MAXC], excl[MAXC], off[MAXC + 1];
  off[0] = 0;
#pragma unroll
  for (int c = 0; c < MAXC; ++c) {
    tot[c]  = rp[c * 256 + 255];
    excl[c] = rp[c * 256 + t] - cnt[c];
    off[c + 1] = off[c] + tot[c];
  }
#pragma unroll
  for (int c = 0; c < MAXC; ++c) {
    int r = off[c] + excl[c];
#pragma unroll
    for (int e = 0; e < 16; ++e)
      if (cv[e] == c) { outpos[base + e] = r; r++; }
  }
  if (t < MAXC) counts[b * MAXC + t] = tot[t];
}

// ---------------- main fused GEMM + online lse stats -----------------------------------
// R14: TLP test.  Ledger: TCP/4 (R4), LDS/2 (R13), VALU diet (R3), pipeline depth
// (R7), overlap (R10), setprio (R11), occupancy 5-16 waves/CU -- ALL null at ~49us.
// The invariant is per-wave instruction count x stalled IPC (issue model ~1000cy/tile
// vs 7350 measured => ~85% stall) with only 2-3 waves/SIMD of TLP.  Test: 16-row
// waves (afr 32 regs, total ~80) + __launch_bounds__(512,6) => 6 waves/SIMD, 24/CU
// -- 2x all previous TLP.  8-wave blocks share the B tile (LDS bytes/FLOP = 2x R7;
// LDS-BW floor ~41us at 85B/cy, accepted).  B just-in-time ds_read (2 reads + 2
// MFMA per ksl) to hold regs <= 85.  3-buffer counted-vmcnt schedule kept (2
// loads/wave/STAGE -> vmcnt(2)).
__global__ __launch_bounds__(512, 6) void k_main(const unsigned short* __restrict__ srcb,
                                                 const unsigned short* __restrict__ tgtb,
                                                 const int* __restrict__ classes,
                                                 float* __restrict__ pm,
                                                 float* __restrict__ ps) {
  __shared__ u32x4 sB[3][1024];               // 3 x 16KB B-tile buffers

  const int p   = blockIdx.x;
  const int b   = p & 3;
  const int jl  = (p >> 2) & 1;
  const int rb  = (p >> 3) & 31;              // 128-row block
  const int top = p >> 8;                     // 0..2
  const int j   = top * 2 + jl;               // 0..5
  const int t0  = (j * 64) / 3;               // 32-col tile range [t0, t1) of 128
  const int t1  = ((j + 1) * 64) / 3;         // chunks: 21,21,22,21,21,22
  const int nt  = t1 - t0;

  const int tid  = threadIdx.x;
  const int w    = tid >> 6;                  // wave 0..7 -> 16-row tile
  const int lane = tid & 63;
  const int q = lane >> 4, l4 = lane & 15;
  const int rowstart = b * NPATCH + rb * 128 + w * 16;

  // ---- A fragments: 16 rows resident per wave (8 coalesced uint4 loads, 32 VGPR)
  const u32x4* ap = (const u32x4*)srcb + (size_t)(b * 256 + rb * 8 + w) * 512 + lane;
  u32x4 afr[8];
#pragma unroll
  for (int ks = 0; ks < 8; ++ks)
    afr[ks] = ap[ks * 64];

  int rcls[4];
#pragma unroll
  for (int r = 0; r < 4; ++r)
    rcls[r] = classes[rowstart + q * 4 + r];

  float m_[4], s_[4];
#pragma unroll
  for (int r = 0; r < 4; ++r) { m_[r] = -INFINITY; s_[r] = 0.f; }

  // ---- staging: 8 waves x 2 glds16 cover the 16KB tile; chunk-group r*8+w
  const u32x4* bstage = (const u32x4*)tgtb + (size_t)(b * 256 + t0 * 2) * 512
                      + w * 64 + lane;
  const int* clp = classes + b * NPATCH + t0 * 32 + l4;

#define STAGE(NB, IT)                                                               \
  {                                                                                 \
    const u32x4* g = bstage + (size_t)(IT) * 1024;                                  \
    glds16(g,       &sB[NB][w * 64]);                                               \
    glds16(g + 512, &sB[NB][(8 + w) * 64]);                                         \
  }

#define STATS(ac, cc0, cc1)                                                         \
  {                                                                                 \
    _Pragma("unroll")                                                               \
    for (int r = 0; r < 4; ++r) {                                                   \
      int rc = rcls[r];                                                             \
      float y0 = ((cc0) == rc) ? NEGH : (ac)[0][r];                                 \
      float y1 = ((cc1) == rc) ? NEGH : (ac)[1][r];                                 \
      float nm = fmaxf(m_[r], fmaxf(y0, y1));                                       \
      float e01 = fexp2(y0 - nm) + fexp2(y1 - nm);                                  \
      s_[r] = fmaf(s_[r], fexp2(m_[r] - nm), e01);                                  \
      m_[r] = nm;                                                                   \
    }                                                                               \
  }

  const f32x4 zc = {0.f, 0.f, 0.f, 0.f};

  STAGE(0, 0);                                // prologue: tiles 0,1 -> bufs 0,1
  STAGE(1, 1);
  asm volatile("s_waitcnt vmcnt(2)\n\ts_barrier" ::: "memory");   // buf0's 2 loads done

  for (int it = 0; it < nt; ++it) {
    const int cb = it % 3;
    const bool staged = (it + 2 < nt);
    if (staged) STAGE((it + 2) % 3, it + 2);  // 2-deep prefetch

    int c0 = clp[0];                          // this tile's column classes
    int c1 = clp[16];
    clp += 32;

    f32x4 acc[2];
    // kh = 0: just-in-time B reads (2 ds_read + 2 MFMA per ksl)
#pragma unroll
    for (int ksl = 0; ksl < 4; ++ksl) {
      u32x4 e0 = sB[cb][ksl * 64 + lane];
      u32x4 e1 = sB[cb][512 + ksl * 64 + lane];
      short8 b0 = __builtin_bit_cast(short8, e0);
      short8 b1 = __builtin_bit_cast(short8, e1);
      short8 a  = __builtin_bit_cast(short8, afr[ksl]);
      acc[0] = __builtin_amdgcn_mfma_f32_16x16x32_bf16(a, b0, (ksl == 0) ? zc : acc[0], 0, 0, 0);
      acc[1] = __builtin_amdgcn_mfma_f32_16x16x32_bf16(a, b1, (ksl == 0) ? zc : acc[1], 0, 0, 0);
    }
    // kh = 1
#pragma unroll
    for (int ksl = 0; ksl < 4; ++ksl) {
      u32x4 e0 = sB[cb][256 + ksl * 64 + lane];
      u32x4 e1 = sB[cb][768 + ksl * 64 + lane];
      short8 b0 = __builtin_bit_cast(short8, e0);
      short8 b1 = __builtin_bit_cast(short8, e1);
      short8 a  = __builtin_bit_cast(short8, afr[4 + ksl]);
      acc[0] = __builtin_amdgcn_mfma_f32_16x16x32_bf16(a, b0, acc[0], 0, 0, 0);
      acc[1] = __builtin_amdgcn_mfma_f32_16x16x32_bf16(a, b1, acc[1], 0, 0, 0);
    }

    STATS(acc, c0, c1);

    if (it + 1 < nt) {
      // counted vmcnt: tile it+2's 2 loads stay in flight; it+1's must be done
      if (staged) asm volatile("s_waitcnt vmcnt(2)\n\ts_barrier" ::: "memory");
      else        asm volatile("s_waitcnt vmcnt(0)\n\ts_barrier" ::: "memory");
    }
  }
#undef STAGE
#undef STATS

  // butterfly merge across the 16 col-lanes of each quad
#pragma unroll
  for (int off = 1; off < 16; off <<= 1) {
#pragma unroll
    for (int r = 0; r < 4; ++r) {
      float om = __shfl_xor(m_[r], off, 64);
      float os = __shfl_xor(s_[r], off, 64);
      float nm = fmaxf(m_[r], om);
      s_[r] = s_[r] * fexp2(m_[r] - nm) + os * fexp2(om - nm);
      m_[r] = nm;
    }
  }

  if (l4 == 0) {
#pragma unroll
    for (int r = 0; r < 4; ++r) {
      size_t o = (size_t)j * NROWS + rowstart + q * 4 + r;
      pm[o] = m_[r];                           // log2 domain
      ps[o] = s_[r];
    }
  }
}

// ---------------- final: merge chunk partials + pad term + scatter --------------------
// R14: grid 64 blocks used only 1/4 of the CUs; widened to 256 x 64.
__global__ __launch_bounds__(64) void k_fin(const int* __restrict__ classes,
                                            const float* __restrict__ pos,
                                            const float* __restrict__ pm,
                                            const float* __restrict__ ps,
                                            const int* __restrict__ outpos,
                                            const int* __restrict__ counts,
                                            float* __restrict__ out) {
  int n = blockIdx.x * 64 + threadIdx.x;
  int b = n >> 12;
  int c = classes[n];
  float ps_ = pos[n];

  float M2 = -INFINITY;
  float mm[NCHUNK], ss[NCHUNK];
#pragma unroll
  for (int s = 0; s < NCHUNK; ++s) {
    mm[s] = pm[(size_t)s * NROWS + n];
    ss[s] = ps[(size_t)s * NROWS + n];
    M2 = fmaxf(M2, mm[s]);
  }
  float S2 = 0.f;
#pragma unroll
  for (int s = 0; s < NCHUNK; ++s) S2 = fmaf(ss[s], fexp2(mm[s] - M2), S2);
  float ln = (S2 > 0.f) ? (M2 + flog2(S2)) * LN2F : -INFINITY;

  int npad = counts[b * MAXC + c] - 1;
  float pt = (npad > 0) ? (logf((float)npad) + NEGFILL_T) : -INFINITY;
  float M = fmaxf(ps_, fmaxf(ln, pt));
  float lse = M + logf(expf(ps_ - M) + expf(ln - M) + expf(pt - M));
  out[b * NPATCH + outpos[n]] = lse - ps_;
}

extern "C" void kernel_launch(void* const* d_in, const int* in_sizes, int n_in,
                              void* d_out, int out_size, void* d_ws, size_t ws_size,
                              hipStream_t stream) {
  const float* src = (const float*)d_in[0];
  const float* tgt = (const float*)d_in[1];
  const int* cls   = (const int*)d_in[2];
  float* out = (float*)d_out;

  char* ws = (char*)d_ws;
  unsigned short* tgtb = (unsigned short*)(ws);            //  8,388,608 B (fragment layout)
  unsigned short* srcb = (unsigned short*)(ws + 8388608);  //  8,388,608 B (frag, pre-scaled)
  float* pos    = (float*)(ws + 16777216);                 //     65,536 B
  float* pm     = (float*)(ws + 16842752);                 //    393,216 B (6 chunk planes)
  float* ps     = (float*)(ws + 17235968);                 //    393,216 B
  int*   outpos = (int*)  (ws + 17629184);                 //     65,536 B
  int*   counts = (int*)  (ws + 17694720);                 //         80 B

  k_aux<<<512 + NBATCH, 256, 0, stream>>>(src, tgt, cls, tgtb, srcb, pos, outpos, counts);
  k_main<<<GRID_MAIN, 512, 0, stream>>>(srcb, tgtb, cls, pm, ps);
  k_fin<<<NROWS / 64, 64, 0, stream>>>(cls, pos, pm, ps, outpos, counts, out);
}

// Round 15
// 124.622 us; speedup vs baseline: 1.0965x; 1.0133x over previous
//
#include <hip/hip_runtime.h>
#include <cstdint>

#define NBATCH 4
#define NPATCH 4096
#define MAXC   5
#define NCHUNK 8                            /* col chunks (j): 16 tiles each */
#define RBLOCKS 16                          /* 256-row blocks per batch */
#define GRID_MAIN (NBATCH * RBLOCKS * NCHUNK)   /* 512 8-wave blocks = 2/CU */
#define SCALE  14.285714285714286f          /* 1/T, T=0.07 */
#define SCALE2 20.609929006188747f          /* (1/T) * log2(e) */
#define LN2F   0.6931471805599453f
#define NEGH  -1.0e38f
#define NEGFILL_T -142.85714285714286f      /* NEG_FILL / T */
#define NROWS (NBATCH * NPATCH)

typedef __attribute__((ext_vector_type(8))) short short8;   // 8 bf16 (4 VGPRs)
typedef __attribute__((ext_vector_type(4))) float f32x4;
typedef __attribute__((ext_vector_type(4))) unsigned int u32x4;

__device__ __forceinline__ float fexp2(float x) { return __builtin_amdgcn_exp2f(x); }
__device__ __forceinline__ float flog2(float x) { return __builtin_amdgcn_logf(x); }  // v_log_f32 = log2

__device__ __forceinline__ unsigned short f2bf(float f) {
  uint32_t u = __builtin_bit_cast(uint32_t, f);
  u = (u + 0x7FFFu + ((u >> 16) & 1u)) >> 16;   // RNE
  return (unsigned short)u;
}

// async global->LDS, 16B per lane; LDS dest is wave-uniform base + lane*16
__device__ __forceinline__ void glds16(const void* g, void* l) {
  __builtin_amdgcn_global_load_lds(
      (const __attribute__((address_space(1))) uint32_t*)g,
      (__attribute__((address_space(3))) uint32_t*)l, 16, 0, 0);
}

// Fragment layout (srcb and tgtb): tile = 16 rows x 256 k (8 KB).
// 16B chunk (8 bf16, one row's k-octet) at uint4 index  tile*512 + kc*16 + row16.

// ---- k_aux: 2 roles ----  (R8 LDS-transpose version, frozen)
__global__ __launch_bounds__(256) void k_aux(const float* __restrict__ src,
                                             const float* __restrict__ tgt,
                                             const int* __restrict__ classes,
                                             unsigned short* __restrict__ tgtb,
                                             unsigned short* __restrict__ srcb,
                                             float* __restrict__ pos,
                                             int* __restrict__ outpos,
                                             int* __restrict__ counts) {
  int blk = blockIdx.x;
  if (blk < 512) {
    __shared__ uint4 sS[2][544], sT[2][544];   // pitch 17 u4 per kc (32 kc x 16 rows)
    int t    = threadIdx.x;
    int half = t >> 7;                         // which tile of the pair
    int tt   = t & 127;
    int tl   = blk * 2 + half;
    int row16 = tt >> 3;                       // 0..15 (read mapping unchanged)
    int kg    = tt & 7;                        // 32-k slab
    size_t rowbase = (size_t)(tl * 16 + row16) * 256 + kg * 32;
    const float4* rs  = (const float4*)(src + rowbase);
    const float4* rt_ = (const float4*)(tgt + rowbase);
    float d = 0.f;
#pragma unroll
    for (int jj = 0; jj < 4; ++jj) {           // chunk kc = kg*4 + jj
      float4 sa = rs[jj * 2], sb = rs[jj * 2 + 1];
      float4 ta = rt_[jj * 2], tb = rt_[jj * 2 + 1];
      d += sa.x * ta.x + sa.y * ta.y + sa.z * ta.z + sa.w * ta.w
         + sb.x * tb.x + sb.y * tb.y + sb.z * tb.z + sb.w * tb.w;
      union { ushort4 h[2]; uint4 u; } pk;
      int li = (kg * 4 + jj) * 17 + row16;
      pk.h[0].x = f2bf(sa.x * SCALE2); pk.h[0].y = f2bf(sa.y * SCALE2);
      pk.h[0].z = f2bf(sa.z * SCALE2); pk.h[0].w = f2bf(sa.w * SCALE2);
      pk.h[1].x = f2bf(sb.x * SCALE2); pk.h[1].y = f2bf(sb.y * SCALE2);
      pk.h[1].z = f2bf(sb.z * SCALE2); pk.h[1].w = f2bf(sb.w * SCALE2);
      sS[half][li] = pk.u;
      pk.h[0].x = f2bf(ta.x); pk.h[0].y = f2bf(ta.y);
      pk.h[0].z = f2bf(ta.z); pk.h[0].w = f2bf(ta.w);
      pk.h[1].x = f2bf(tb.x); pk.h[1].y = f2bf(tb.y);
      pk.h[1].z = f2bf(tb.z); pk.h[1].w = f2bf(tb.w);
      sT[half][li] = pk.u;
    }
    d += __shfl_xor(d, 1, 64);
    d += __shfl_xor(d, 2, 64);
    d += __shfl_xor(d, 4, 64);
    if (kg == 0) pos[tl * 16 + row16] = d * SCALE;

    __syncthreads();
    // coalesced store: 128 consecutive lanes cover 2KB contiguous fragment span
    uint4* osrc = (uint4*)srcb + (size_t)tl * 512;
    uint4* otgt = (uint4*)tgtb + (size_t)tl * 512;
#pragma unroll
    for (int c = 0; c < 4; ++c) {
      int g  = c * 128 + tt;                   // u4 index within tile (0..511)
      int li = (g >> 4) * 17 + (g & 15);
      osrc[g] = sS[half][li];
      otgt[g] = sT[half][li];
    }
    return;
  }

  __shared__ int sa[MAXC * 256];
  __shared__ int sb2[MAXC * 256];
  int b = blk - 512, t = threadIdx.x;
  int base = b * NPATCH + t * 16;
  int cv[16];
#pragma unroll
  for (int e = 0; e < 16; ++e) cv[e] = classes[base + e];
  int cnt[MAXC];
#pragma unroll
  for (int c = 0; c < MAXC; ++c) {
    cnt[c] = 0;
#pragma unroll
    for (int e = 0; e < 16; ++e)
      if (cv[e] == c) cnt[c]++;
  }
#pragma unroll
  for (int c = 0; c < MAXC; ++c) sa[c * 256 + t] = cnt[c];
  __syncthreads();

  int* rp = sa; int* wp = sb2;
  for (int d = 1; d < 256; d <<= 1) {
#pragma unroll
    for (int c = 0; c < MAXC; ++c) {
      int v = rp[c * 256 + t];
      if (t >= d) v += rp[c * 256 + t - d];
      wp[c * 256 + t] = v;
    }
    __syncthreads();
    int* tmp = rp; rp = wp; wp = tmp;
  }

  int tot[MAXC], excl[MAXC], off[MAXC + 1];
  off[0] = 0;
#pragma unroll
  for (int c = 0; c < MAXC; ++c) {
    tot[c]  = rp[c * 256 + 255];
    excl[c] = rp[c * 256 + t] - cnt[c];
    off[c + 1] = off[c] + tot[c];
  }
#pragma unroll
  for (int c = 0; c < MAXC; ++c) {
    int r = off[c] + excl[c];
#pragma unroll
    for (int e = 0; e < 16; ++e)
      if (cv[e] == c) { outpos[base + e] = r; r++; }
  }
  if (t < MAXC) counts[b * MAXC + t] = tot[t];
}

// ---------------- main fused GEMM + online lse stats -----------------------------------
// R15: roofline move.  R14 measured: occupancy 47%, 73 B/cy/CU LDS reads = 86% of the
// 85 B/cy ceiling -> FIRST genuinely resource-bound config (LDS read BW).  Fix: keep
// R14's TLP (16 waves/CU), halve LDS bytes/FLOP: 32-row waves (afr 64 regs, fits 4
// waves/SIMD at <=128 VGPR cap), 8-wave blocks of 256 rows sharing each B tile.
// Total LDS reads 2.1 GB -> 1.05 GB (floor ~20-23us).  Inner loop = R7's proven JIT
// pattern (2 ds_read + 4 MFMA per ksl); staging = R14's 2-load/wave STAGE, counted
// vmcnt(2); 3-buffer rotation; NCHUNK=8 (nt=16), grid 512 = 2 blocks/CU.
__global__ __launch_bounds__(512, 4) void k_main(const unsigned short* __restrict__ srcb,
                                                 const unsigned short* __restrict__ tgtb,
                                                 const int* __restrict__ classes,
                                                 float* __restrict__ pm,
                                                 float* __restrict__ ps) {
  __shared__ u32x4 sB[3][1024];               // 3 x 16KB B-tile buffers

  const int p   = blockIdx.x;
  const int b   = p & 3;
  const int jl  = (p >> 2) & 1;
  const int rb  = (p >> 3) & 15;              // 256-row block
  const int top = p >> 7;                     // 0..3
  const int j   = top * 2 + jl;               // chunk 0..7
  const int t0  = j * 16;                     // 16 32-col tiles per chunk
  const int nt  = 16;

  const int tid  = threadIdx.x;
  const int w    = tid >> 6;                  // wave 0..7 -> 32-row group
  const int lane = tid & 63;
  const int q = lane >> 4, l4 = lane & 15;
  const int rowstart = b * NPATCH + rb * 256 + w * 32;

  // ---- A fragments: 32 rows resident per wave (16 coalesced uint4 loads, 64 VGPR)
  const u32x4* ap = (const u32x4*)srcb + (size_t)(b * 256 + rb * 16 + w * 2) * 512 + lane;
  u32x4 afr[2][8];
#pragma unroll
  for (int rt = 0; rt < 2; ++rt)
#pragma unroll
    for (int ks = 0; ks < 8; ++ks)
      afr[rt][ks] = ap[rt * 512 + ks * 64];

  int rcls[2][4];
#pragma unroll
  for (int rt = 0; rt < 2; ++rt)
#pragma unroll
    for (int r = 0; r < 4; ++r)
      rcls[rt][r] = classes[rowstart + rt * 16 + q * 4 + r];

  float m_[2][4], s_[2][4];
#pragma unroll
  for (int rt = 0; rt < 2; ++rt)
#pragma unroll
    for (int r = 0; r < 4; ++r) { m_[rt][r] = -INFINITY; s_[rt][r] = 0.f; }

  // ---- staging: 8 waves x 2 glds16 cover the 16KB tile
  const u32x4* bstage = (const u32x4*)tgtb + (size_t)(b * 256 + t0 * 2) * 512
                      + w * 64 + lane;
  const int* clp = classes + b * NPATCH + t0 * 32 + l4;

#define STAGE(NB, IT)                                                               \
  {                                                                                 \
    const u32x4* g = bstage + (size_t)(IT) * 1024;                                  \
    glds16(g,       &sB[NB][w * 64]);                                               \
    glds16(g + 512, &sB[NB][(8 + w) * 64]);                                         \
  }

#define STATS(ac, cc0, cc1)                                                         \
  {                                                                                 \
    _Pragma("unroll")                                                               \
    for (int rt = 0; rt < 2; ++rt) {                                                \
      _Pragma("unroll")                                                             \
      for (int r = 0; r < 4; ++r) {                                                 \
        int rc = rcls[rt][r];                                                       \
        float y0 = ((cc0) == rc) ? NEGH : (ac)[rt][0][r];                           \
        float y1 = ((cc1) == rc) ? NEGH : (ac)[rt][1][r];                           \
        float nm = fmaxf(m_[rt][r], fmaxf(y0, y1));                                 \
        float e01 = fexp2(y0 - nm) + fexp2(y1 - nm);                                \
        s_[rt][r] = fmaf(s_[rt][r], fexp2(m_[rt][r] - nm), e01);                    \
        m_[rt][r] = nm;                                                             \
      }                                                                             \
    }                                                                               \
  }

  const f32x4 zc = {0.f, 0.f, 0.f, 0.f};

  STAGE(0, 0);                                // prologue: tiles 0,1 -> bufs 0,1
  STAGE(1, 1);
  asm volatile("s_waitcnt vmcnt(2)\n\ts_barrier" ::: "memory");   // buf0's 2 loads done

  for (int it = 0; it < nt; ++it) {
    const int cb = it % 3;
    const bool staged = (it + 2 < nt);
    if (staged) STAGE((it + 2) % 3, it + 2);  // 2-deep prefetch

    int c0 = clp[0];                          // this tile's column classes
    int c1 = clp[16];
    clp += 32;

    f32x4 acc[2][2];
    // kh = 0: just-in-time B reads (2 ds_read + 4 MFMA per ksl)
#pragma unroll
    for (int ksl = 0; ksl < 4; ++ksl) {
      u32x4 e0 = sB[cb][ksl * 64 + lane];
      u32x4 e1 = sB[cb][512 + ksl * 64 + lane];
      short8 b0 = __builtin_bit_cast(short8, e0);
      short8 b1 = __builtin_bit_cast(short8, e1);
#pragma unroll
      for (int rt = 0; rt < 2; ++rt) {
        short8 a = __builtin_bit_cast(short8, afr[rt][ksl]);
        acc[rt][0] = __builtin_amdgcn_mfma_f32_16x16x32_bf16(
            a, b0, (ksl == 0) ? zc : acc[rt][0], 0, 0, 0);
        acc[rt][1] = __builtin_amdgcn_mfma_f32_16x16x32_bf16(
            a, b1, (ksl == 0) ? zc : acc[rt][1], 0, 0, 0);
      }
    }
    // kh = 1
#pragma unroll
    for (int ksl = 0; ksl < 4; ++ksl) {
      u32x4 e0 = sB[cb][256 + ksl * 64 + lane];
      u32x4 e1 = sB[cb][768 + ksl * 64 + lane];
      short8 b0 = __builtin_bit_cast(short8, e0);
      short8 b1 = __builtin_bit_cast(short8, e1);
#pragma unroll
      for (int rt = 0; rt < 2; ++rt) {
        short8 a = __builtin_bit_cast(short8, afr[rt][4 + ksl]);
        acc[rt][0] = __builtin_amdgcn_mfma_f32_16x16x32_bf16(a, b0, acc[rt][0], 0, 0, 0);
        acc[rt][1] = __builtin_amdgcn_mfma_f32_16x16x32_bf16(a, b1, acc[rt][1], 0, 0, 0);
      }
    }

    STATS(acc, c0, c1);

    if (it + 1 < nt) {
      // counted vmcnt: tile it+2's 2 loads stay in flight; it+1's must be done
      if (staged) asm volatile("s_waitcnt vmcnt(2)\n\ts_barrier" ::: "memory");
      else        asm volatile("s_waitcnt vmcnt(0)\n\ts_barrier" ::: "memory");
    }
  }
#undef STAGE
#undef STATS

  // butterfly merge across the 16 col-lanes of each quad
#pragma unroll
  for (int off = 1; off < 16; off <<= 1) {
#pragma unroll
    for (int rt = 0; rt < 2; ++rt)
#pragma unroll
      for (int r = 0; r < 4; ++r) {
        float om = __shfl_xor(m_[rt][r], off, 64);
        float os = __shfl_xor(s_[rt][r], off, 64);
        float nm = fmaxf(m_[rt][r], om);
        s_[rt][r] = s_[rt][r] * fexp2(m_[rt][r] - nm) + os * fexp2(om - nm);
        m_[rt][r] = nm;
      }
  }

  if (l4 == 0) {
#pragma unroll
    for (int rt = 0; rt < 2; ++rt)
#pragma unroll
      for (int r = 0; r < 4; ++r) {
        size_t o = (size_t)j * NROWS + rowstart + rt * 16 + q * 4 + r;
        pm[o] = m_[rt][r];                     // log2 domain
        ps[o] = s_[rt][r];
      }
  }
}

// ---------------- final: merge chunk partials + pad term + scatter --------------------
__global__ __launch_bounds__(64) void k_fin(const int* __restrict__ classes,
                                            const float* __restrict__ pos,
                                            const float* __restrict__ pm,
                                            const float* __restrict__ ps,
                                            const int* __restrict__ outpos,
                                            const int* __restrict__ counts,
                                            float* __restrict__ out) {
  int n = blockIdx.x * 64 + threadIdx.x;
  int b = n >> 12;
  int c = classes[n];
  float ps_ = pos[n];

  float M2 = -INFINITY;
  float mm[NCHUNK], ss[NCHUNK];
#pragma unroll
  for (int s = 0; s < NCHUNK; ++s) {
    mm[s] = pm[(size_t)s * NROWS + n];
    ss[s] = ps[(size_t)s * NROWS + n];
    M2 = fmaxf(M2, mm[s]);
  }
  float S2 = 0.f;
#pragma unroll
  for (int s = 0; s < NCHUNK; ++s) S2 = fmaf(ss[s], fexp2(mm[s] - M2), S2);
  float ln = (S2 > 0.f) ? (M2 + flog2(S2)) * LN2F : -INFINITY;

  int npad = counts[b * MAXC + c] - 1;
  float pt = (npad > 0) ? (logf((float)npad) + NEGFILL_T) : -INFINITY;
  float M = fmaxf(ps_, fmaxf(ln, pt));
  float lse = M + logf(expf(ps_ - M) + expf(ln - M) + expf(pt - M));
  out[b * NPATCH + outpos[n]] = lse - ps_;
}

extern "C" void kernel_launch(void* const* d_in, const int* in_sizes, int n_in,
                              void* d_out, int out_size, void* d_ws, size_t ws_size,
                              hipStream_t stream) {
  const float* src = (const float*)d_in[0];
  const float* tgt = (const float*)d_in[1];
  const int* cls   = (const int*)d_in[2];
  float* out = (float*)d_out;

  char* ws = (char*)d_ws;
  unsigned short* tgtb = (unsigned short*)(ws);            //  8,388,608 B (fragment layout)
  unsigned short* srcb = (unsigned short*)(ws + 8388608);  //  8,388,608 B (frag, pre-scaled)
  float* pos    = (float*)(ws + 16777216);                 //     65,536 B
  float* pm     = (float*)(ws + 16842752);                 //    524,288 B (8 chunk planes)
  float* ps     = (float*)(ws + 17367040);                 //    524,288 B
  int*   outpos = (int*)  (ws + 17891328);                 //     65,536 B
  int*   counts = (int*)  (ws + 17956864);                 //         80 B

  k_aux<<<512 + NBATCH, 256, 0, stream>>>(src, tgt, cls, tgtb, srcb, pos, outpos, counts);
  k_main<<<GRID_MAIN, 512, 0, stream>>>(srcb, tgtb, cls, pm, ps);
  k_fin<<<NROWS / 64, 64, 0, stream>>>(cls, pos, pm, ps, outpos, counts, out);
}